// Round 1
// baseline (56.646 us; speedup 1.0000x reference)
//
#include <hip/hip_runtime.h>

#define NQ 12
#define NSTATE 4096
#define NL 5
#define TPB 256

// LDS slot swizzle: XOR bits 4..7 into bits 0..3 -> all gate passes hit the
// ds_read_b64 bank floor (4 lanes/bank-pair, distinct addrs) instead of the
// 32-way conflict of contiguous 128B-stride chunks.
__device__ __forceinline__ int swz(int i) { return i ^ ((i >> 4) & 15); }

// Composition of the full CNOT ring CNOT(q, (q+1)%12), q=0..11 (qubit q = bit 11-q):
// new_state[i] = old_state[f(i)],  f(i) = i ^ (i>>1) ^ (bit0(i) ? 0xC00 : 0).
// Derived per basis vector: f(e_b) = {b-1, b} for b>=1; f(e_0) = {0, 10, 11}.
__device__ __forceinline__ int permf(int i) {
    return i ^ (i >> 1) ^ ((-(i & 1)) & 0xC00);
}

// Apply a single-qubit gate on nibble-bit K of the 16 in-register amplitudes.
template <int K>
__device__ __forceinline__ void apply_gate(float2 (&v)[16], const float2* __restrict__ Uq) {
    const float2 u00 = Uq[0], u01 = Uq[1], u10 = Uq[2], u11 = Uq[3];
#pragma unroll
    for (int h = 0; h < 8; ++h) {
        const int m0 = ((h >> K) << (K + 1)) | (h & ((1 << K) - 1));
        const int m1 = m0 | (1 << K);
        const float2 a = v[m0], c = v[m1];
        float2 n0, n1;
        n0.x = fmaf(u00.x, a.x, fmaf(-u00.y, a.y, fmaf(u01.x, c.x, -u01.y * c.y)));
        n0.y = fmaf(u00.x, a.y, fmaf( u00.y, a.x, fmaf(u01.x, c.y,  u01.y * c.x)));
        n1.x = fmaf(u10.x, a.x, fmaf(-u10.y, a.y, fmaf(u11.x, c.x, -u11.y * c.y)));
        n1.y = fmaf(u10.x, a.y, fmaf( u10.y, a.x, fmaf(u11.x, c.y,  u11.y * c.x)));
        v[m0] = n0;
        v[m1] = n1;
    }
}

extern "C" __global__ void __launch_bounds__(TPB)
qnet_kernel(const float* __restrict__ x, const float* __restrict__ iw,
            const float* __restrict__ th, const float* __restrict__ ow,
            float* __restrict__ out) {
    __shared__ float2 st[NSTATE];        // 32 KB state (swizzled slots)
    __shared__ float2 U[NL][NQ][4];      // per-layer per-qubit 2x2 complex gates
    __shared__ float wz[4][4];           // per-wave partial Z sums

    const int b = blockIdx.x;
    const int tid = threadIdx.x;

    // --- init state |0...0> ---
#pragma unroll
    for (int r = 0; r < 16; ++r) st[tid * 16 + r] = make_float2(0.f, 0.f);
    if (tid == 0) st[0] = make_float2(1.f, 0.f);  // swz(0) == 0

    // --- precompute all 60 gate matrices U = M(b,c) @ Rx(a) ---
    if (tid < NL * NQ) {
        const int l = tid / NQ, q = tid % NQ;
        const float xv = tanhf(x[b * NQ + q]);
        const float a = iw[l * NQ + q] * xv;
        const float bt = th[(l * NQ + q) * 2 + 0];
        const float ct = th[(l * NQ + q) * 2 + 1];
        float sa, ca; sincosf(0.5f * a, &sa, &ca);
        float sb, cb; sincosf(0.5f * bt, &sb, &cb);
        float sc, cc; sincosf(0.5f * ct, &sc, &cc);
        // ec = exp(-i c/2) = cc - i sc
        const float M00r = cc * cb, M00i = -sc * cb;
        const float M01r = -cc * sb, M01i = sc * sb;
        const float M10r = cc * sb, M10i = sc * sb;
        const float M11r = cc * cb, M11i = sc * cb;
        // Rx = [[ca, -i sa], [-i sa, ca]];  U = M @ Rx
        U[l][q][0] = make_float2(fmaf(M00r, ca,  sa * M01i), fmaf(M00i, ca, -sa * M01r));
        U[l][q][1] = make_float2(fmaf(ca, M01r,  sa * M00i), fmaf(ca, M01i, -sa * M00r));
        U[l][q][2] = make_float2(fmaf(M10r, ca,  sa * M11i), fmaf(M10i, ca, -sa * M11r));
        U[l][q][3] = make_float2(fmaf(ca, M11r,  sa * M10i), fmaf(ca, M11i, -sa * M10r));
    }
    __syncthreads();

    for (int l = 0; l < NL; ++l) {
        float2 v[16];

        // --- pass A: bits 0..3 (qubits 11..8); gather fuses previous layer's CNOT perm ---
#pragma unroll
        for (int r = 0; r < 16; ++r) {
            const int i = tid * 16 + r;
            const int j = (l == 0) ? i : permf(i);
            v[r] = st[swz(j)];
        }
        if (l > 0) __syncthreads();  // reads (into regs) done before anyone overwrites
        apply_gate<0>(v, U[l][11]);
        apply_gate<1>(v, U[l][10]);
        apply_gate<2>(v, U[l][9]);
        apply_gate<3>(v, U[l][8]);
#pragma unroll
        for (int r = 0; r < 16; ++r) st[swz(tid * 16 + r)] = v[r];
        __syncthreads();

        // --- pass B: bits 4..7 (qubits 7..4) ---
        {
            const int lo = tid & 15, hi = tid >> 4;
            const int base = (hi << 8) | lo;
#pragma unroll
            for (int m = 0; m < 16; ++m) v[m] = st[swz(base | (m << 4))];
            apply_gate<0>(v, U[l][7]);
            apply_gate<1>(v, U[l][6]);
            apply_gate<2>(v, U[l][5]);
            apply_gate<3>(v, U[l][4]);
#pragma unroll
            for (int m = 0; m < 16; ++m) st[swz(base | (m << 4))] = v[m];
        }
        __syncthreads();

        // --- pass C: bits 8..11 (qubits 3..0) ---
        {
#pragma unroll
            for (int m = 0; m < 16; ++m) v[m] = st[swz((m << 8) | tid)];
            apply_gate<0>(v, U[l][3]);
            apply_gate<1>(v, U[l][2]);
            apply_gate<2>(v, U[l][1]);
            apply_gate<3>(v, U[l][0]);
#pragma unroll
            for (int m = 0; m < 16; ++m) st[swz((m << 8) | tid)] = v[m];
        }
        __syncthreads();
    }

    // --- final CNOT perm fused into measurement ---
    float ps = 0.f;
#pragma unroll
    for (int r = 0; r < 16; ++r) {
        const int i = tid * 16 + r;
        const float2 a = st[swz(permf(i))];
        ps = fmaf(a.x, a.x, fmaf(a.y, a.y, ps));
    }
    // Z on qubits 0..3 = bits 11..8 of i = bits 7..4 of tid (constant per thread)
    float s0 = (tid & 128) ? -ps : ps;
    float s1 = (tid & 64) ? -ps : ps;
    float s2 = (tid & 32) ? -ps : ps;
    float s3 = (tid & 16) ? -ps : ps;
#pragma unroll
    for (int off = 32; off > 0; off >>= 1) {
        s0 += __shfl_xor(s0, off);
        s1 += __shfl_xor(s1, off);
        s2 += __shfl_xor(s2, off);
        s3 += __shfl_xor(s3, off);
    }
    const int wave = tid >> 6;
    if ((tid & 63) == 0) {
        wz[wave][0] = s0; wz[wave][1] = s1; wz[wave][2] = s2; wz[wave][3] = s3;
    }
    __syncthreads();
    if (tid < 4) {
        const float z = wz[0][tid] + wz[1][tid] + wz[2][tid] + wz[3][tid];
        out[b * 4 + tid] = ow[tid] * z;
    }
}

extern "C" void kernel_launch(void* const* d_in, const int* in_sizes, int n_in,
                              void* d_out, int out_size, void* d_ws, size_t ws_size,
                              hipStream_t stream) {
    const float* x  = (const float*)d_in[0];
    const float* iw = (const float*)d_in[1];
    const float* th = (const float*)d_in[2];
    const float* ow = (const float*)d_in[3];
    float* out = (float*)d_out;
    const int batch = in_sizes[0] / NQ;
    hipLaunchKernelGGL(qnet_kernel, dim3(batch), dim3(TPB), 0, stream,
                       x, iw, th, ow, out);
}